// Round 1
// baseline (697.795 us; speedup 1.0000x reference)
//
#include <hip/hip_runtime.h>
#include <math.h>

#define Bd   4
#define Td   4
#define Cd   32
#define Nd   16384
#define Fd   64
#define Kd   9
#define PADd 4
#define NT   256
#define NTP  (NT + 2*PADd)   // 264

// sigma arrives as a 1-element array; reference says Python int -> int32.
// Be robust to either int32 or float32 storage.
__device__ __forceinline__ float sigma_as_float(const void* p) {
    int iv = *(const int*)p;
    if (iv > 0 && iv < 1000000) return (float)iv;   // plausible small int
    return __int_as_float(iv);                      // actually a float bit-pattern
}

__global__ __launch_bounds__(256, 4)
void swconv_f32_kernel(const float* __restrict__ x,
                       const float* __restrict__ coords,
                       const float* __restrict__ weight,
                       const void*  __restrict__ sigma_p,
                       float* __restrict__ out)
{
    __shared__ float xs[Cd][NTP];   // x tile with halo: 32*264*4 = 33792 B
    __shared__ float cs[3][NTP];    // coords tile with halo: 3168 B

    const int tid  = threadIdx.x;
    const int tile = blockIdx.x;      // n-tile index
    const int t    = blockIdx.y;
    const int b    = blockIdx.z;
    const int n0   = tile * NT;

    const float inv_sigma = 1.0f / sigma_as_float(sigma_p);

    // ---- stage x tile (zero-padded halo) ----
    const float* xbt = x + (size_t)(b*Td + t) * Cd * Nd;
    #pragma unroll 4
    for (int idx = tid; idx < Cd*NTP; idx += 256) {
        int c = idx / NTP;
        int i = idx - c*NTP;
        int n = n0 - PADd + i;
        xs[c][i] = (n >= 0 && n < Nd) ? xbt[(size_t)c*Nd + n] : 0.0f;
    }
    // ---- stage coords tile (zero-padded halo) ----
    const float* cbt = coords + (size_t)(b*Td + t) * 3 * Nd;
    for (int idx = tid; idx < 3*NTP; idx += 256) {
        int c = idx / NTP;
        int i = idx - c*NTP;
        int n = n0 - PADd + i;
        cs[c][i] = (n >= 0 && n < Nd) ? cbt[(size_t)c*Nd + n] : 0.0f;
    }
    __syncthreads();

    // ---- distance weights for this thread's n (kept in registers) ----
    float wk[Kd];
    {
        const float c0 = cs[0][tid + PADd];
        const float c1 = cs[1][tid + PADd];
        const float c2 = cs[2][tid + PADd];
        #pragma unroll
        for (int k = 0; k < Kd; ++k) {
            float d0 = cs[0][tid + k] - c0;
            float d1 = cs[1][tid + k] - c1;
            float d2 = cs[2][tid + k] - c2;
            float s  = d0*d0 + d1*d1 + d2*d2;
            float d  = (s > 0.0f) ? sqrtf(s) : 0.0f;   // safe sqrt, matches ref
            wk[k] = fmaxf(1.0f - d * inv_sigma, 0.0f);
        }
    }

    // ---- accumulate all 64 output features for this n ----
    float acc[Fd];
    #pragma unroll
    for (int f = 0; f < Fd; ++f) acc[f] = 0.0f;

    // weight[t][f][c][k]; t is block-uniform -> scalar loads
    const float* wt = weight + (size_t)t * Fd * Cd * Kd;

    for (int c = 0; c < Cd; ++c) {
        // 9 overlapping LDS reads for this channel's window
        float xv[Kd];
        #pragma unroll
        for (int k = 0; k < Kd; ++k) xv[k] = xs[c][tid + k];

        const float* wp = wt + c*Kd;   // uniform base for this (t, c)
        #pragma unroll
        for (int k = 0; k < Kd; ++k) {
            float v = xv[k] * wk[k];
            #pragma unroll
            for (int f = 0; f < Fd; ++f) {
                acc[f] = fmaf(v, wp[(size_t)f*Cd*Kd + k], acc[f]);
            }
        }
    }

    // ---- store: out[b][t][f][n], lanes contiguous in n -> coalesced ----
    float* op = out + (size_t)(b*Td + t) * Fd * Nd + n0 + tid;
    #pragma unroll
    for (int f = 0; f < Fd; ++f) op[(size_t)f*Nd] = acc[f];
}

extern "C" void kernel_launch(void* const* d_in, const int* in_sizes, int n_in,
                              void* d_out, int out_size, void* d_ws, size_t ws_size,
                              hipStream_t stream) {
    const float* x      = (const float*)d_in[0];
    const float* coords = (const float*)d_in[1];
    const float* weight = (const float*)d_in[2];
    const void*  sigma  = d_in[3];
    float* out = (float*)d_out;

    dim3 grid(Nd / NT, Td, Bd);   // 64 x 4 x 4 = 1024 blocks
    dim3 block(256);
    swconv_f32_kernel<<<grid, block, 0, stream>>>(x, coords, weight, sigma, out);
}

// Round 2
// 140.641 us; speedup vs baseline: 4.9615x; 4.9615x over previous
//
#include <hip/hip_runtime.h>
#include <hip/hip_bf16.h>
#include <math.h>

#define Bd   4
#define Td   4
#define Cd   32
#define Nd   16384
#define Fd   64
#define Kd   9
#define PADd 4
#define NT   256
#define NROWS (NT + 2*PADd)   // 264 rows of staged x (with halo)
#define XPITCH 40             // ushorts per xs row: 32 + 8 pad (rows r, r+8 share banks -> free 2-way)

typedef __attribute__((ext_vector_type(8))) short  short8;   // 8 bf16 (4 VGPRs) — MFMA A/B frag
typedef __attribute__((ext_vector_type(4))) float  float4v;  // MFMA acc frag

#define A_WS_BYTES ((size_t)Td * Kd * 4 * 64 * 8 * 2)  // 147456

// sigma is a 1-element array; robust to int32 or float32 storage.
__device__ __forceinline__ float sigma_as_float(const void* p) {
    int iv = *(const int*)p;
    if (iv > 0 && iv < 1000000) return (float)iv;
    return __int_as_float(iv);
}

// RNE pack: two fp32 products -> packed bf16x2 (no API dependency)
__device__ __forceinline__ unsigned int mul_bf16pair(unsigned int p, float w) {
    float lo = __uint_as_float(p << 16) * w;
    float hi = __uint_as_float(p & 0xffff0000u) * w;
    unsigned int a = __float_as_uint(lo), b = __float_as_uint(hi);
    a += 0x7fffu + ((a >> 16) & 1u);
    b += 0x7fffu + ((b >> 16) & 1u);
    return (a >> 16) | (b & 0xffff0000u);
}

__device__ __forceinline__ unsigned short f32_to_bf16_rne(float v) {
    unsigned int a = __float_as_uint(v);
    a += 0x7fffu + ((a >> 16) & 1u);
    return (unsigned short)(a >> 16);
}

// ---- prep: weight fp32 [T][F][C][K] -> A bf16 in ws, MFMA-A-fragment order ----
// A_ws index = (((t*K + k)*4 + ft)*64 + lane)*8 + j ;  value = W[t][ft*16+(lane&15)][(lane>>4)*8+j][k]
__global__ void prep_weights(const float* __restrict__ w, unsigned short* __restrict__ a) {
    int idx = blockIdx.x * 256 + threadIdx.x;
    if (idx >= Td * Kd * 4 * 64 * 8) return;
    int j    = idx & 7;
    int lane = (idx >> 3) & 63;
    int ft   = (idx >> 9) & 3;
    int k    = (idx >> 11) % Kd;
    int t    = idx / (Kd * 4 * 64 * 8);
    int m = lane & 15, q = lane >> 4;
    int f = ft * 16 + m;
    int c = q * 8 + j;
    float v = w[(((size_t)t * Fd + f) * Cd + c) * Kd + k];
    a[idx] = f32_to_bf16_rne(v);
}

// ---- main MFMA kernel ----
__global__ __launch_bounds__(256)
void swconv_mfma(const float* __restrict__ x,
                 const float* __restrict__ coords,
                 const unsigned short* __restrict__ aw,
                 const void* __restrict__ sigma_p,
                 float* __restrict__ out)
{
    __shared__ __align__(16) unsigned short xs[NROWS][XPITCH]; // 21120 B, x transposed bf16
    __shared__ float wl[Kd][NT];                               // 9216 B, distance weights

    const int tid  = threadIdx.x;
    const int lane = tid & 63;
    const int wv   = tid >> 6;          // wave id 0..3, owns n_local [64*wv, 64*wv+64)
    const int tile = blockIdx.x, t = blockIdx.y, b = blockIdx.z;
    const int n0   = tile * NT;
    const float inv_sigma = 1.0f / sigma_as_float(sigma_p);

    // stage x tile -> bf16, transposed: xs[r][c] = x[c][n0-4+r]
    const float* xbt = x + (size_t)(b * Td + t) * Cd * Nd;
    for (int idx = tid; idx < Cd * NROWS; idx += 256) {
        int c = idx / NROWS;
        int r = idx - c * NROWS;
        int n = n0 - PADd + r;
        float v = (n >= 0 && n < Nd) ? xbt[(size_t)c * Nd + n] : 0.0f;
        xs[r][c] = f32_to_bf16_rne(v);
    }

    // distance weights wl[k][n_local] for this thread's n
    {
        const float* cbt = coords + (size_t)(b * Td + t) * 3 * Nd;
        int n = n0 + tid;                       // always in [0, Nd)
        float c0 = cbt[n], c1 = cbt[Nd + n], c2 = cbt[2 * Nd + n];
        #pragma unroll
        for (int k = 0; k < Kd; ++k) {
            int nn = n + k - PADd;
            float d0, d1, d2;
            if (nn >= 0 && nn < Nd) {
                d0 = cbt[nn] - c0; d1 = cbt[Nd + nn] - c1; d2 = cbt[2 * Nd + nn] - c2;
            } else {                            // zero-padded coords
                d0 = -c0; d1 = -c1; d2 = -c2;
            }
            float s = d0 * d0 + d1 * d1 + d2 * d2;
            float d = (s > 0.0f) ? sqrtf(s) : 0.0f;
            wl[k][tid] = fmaxf(1.0f - d * inv_sigma, 0.0f);
        }
    }
    __syncthreads();

    const int m = lane & 15, q = lane >> 4;
    const unsigned short* At = aw + (size_t)t * Kd * 4 * 64 * 8;

    float4v acc[4][4];
    #pragma unroll
    for (int ft = 0; ft < 4; ++ft)
        #pragma unroll
        for (int nt = 0; nt < 4; ++nt)
            acc[ft][nt] = (float4v){0.f, 0.f, 0.f, 0.f};

    const int ncol_base = wv * 64 + m;

    for (int k = 0; k < Kd; ++k) {
        // A fragments: 4 coalesced 16B loads from L2-hot prepped weights
        short8 afr[4];
        #pragma unroll
        for (int ft = 0; ft < 4; ++ft) {
            const short8* p = (const short8*)(At + (((size_t)(k * 4 + ft)) * 64 + lane) * 8);
            afr[ft] = *p;
        }
        #pragma unroll
        for (int nt = 0; nt < 4; ++nt) {
            const int ncol = ncol_base + nt * 16;   // n_local of this lane's column
            const int r    = ncol + k;              // xs row = n_local + k
            uint4 pv = *reinterpret_cast<const uint4*>(&xs[r][q * 8]);  // ds_read_b128: 8 bf16, c=q*8..q*8+7
            float wgt = wl[k][ncol];
            unsigned int u0 = mul_bf16pair(pv.x, wgt);
            unsigned int u1 = mul_bf16pair(pv.y, wgt);
            unsigned int u2 = mul_bf16pair(pv.z, wgt);
            unsigned int u3 = mul_bf16pair(pv.w, wgt);
            uint4 packed = {u0, u1, u2, u3};
            short8 bfr = *reinterpret_cast<short8*>(&packed);
            #pragma unroll
            for (int ft = 0; ft < 4; ++ft)
                acc[ft][nt] = __builtin_amdgcn_mfma_f32_16x16x32_bf16(afr[ft], bfr, acc[ft][nt], 0, 0, 0);
        }
    }

    // epilogue: C/D layout col=lane&15, row=(lane>>4)*4+reg
    float* ob = out + (size_t)(b * Td + t) * Fd * Nd + n0;
    #pragma unroll
    for (int ft = 0; ft < 4; ++ft) {
        #pragma unroll
        for (int nt = 0; nt < 4; ++nt) {
            const int ncol = ncol_base + nt * 16;
            #pragma unroll
            for (int rr = 0; rr < 4; ++rr) {
                int f = ft * 16 + q * 4 + rr;
                ob[(size_t)f * Nd + ncol] = acc[ft][nt][rr];
            }
        }
    }
}

// ---- fallback (round-1 fp32 kernel) in case ws is too small for A ----
__global__ __launch_bounds__(256, 4)
void swconv_f32_kernel(const float* __restrict__ x,
                       const float* __restrict__ coords,
                       const float* __restrict__ weight,
                       const void*  __restrict__ sigma_p,
                       float* __restrict__ out)
{
    __shared__ float xsf[Cd][NROWS];
    __shared__ float csf[3][NROWS];
    const int tid = threadIdx.x;
    const int tile = blockIdx.x, t = blockIdx.y, b = blockIdx.z;
    const int n0 = tile * NT;
    const float inv_sigma = 1.0f / sigma_as_float(sigma_p);

    const float* xbt = x + (size_t)(b * Td + t) * Cd * Nd;
    for (int idx = tid; idx < Cd * NROWS; idx += 256) {
        int c = idx / NROWS, i = idx - c * NROWS, n = n0 - PADd + i;
        xsf[c][i] = (n >= 0 && n < Nd) ? xbt[(size_t)c * Nd + n] : 0.0f;
    }
    const float* cbt = coords + (size_t)(b * Td + t) * 3 * Nd;
    for (int idx = tid; idx < 3 * NROWS; idx += 256) {
        int c = idx / NROWS, i = idx - c * NROWS, n = n0 - PADd + i;
        csf[c][i] = (n >= 0 && n < Nd) ? cbt[(size_t)c * Nd + n] : 0.0f;
    }
    __syncthreads();

    float wk[Kd];
    {
        const float c0 = csf[0][tid + PADd], c1 = csf[1][tid + PADd], c2 = csf[2][tid + PADd];
        #pragma unroll
        for (int k = 0; k < Kd; ++k) {
            float d0 = csf[0][tid + k] - c0, d1 = csf[1][tid + k] - c1, d2 = csf[2][tid + k] - c2;
            float s = d0 * d0 + d1 * d1 + d2 * d2;
            float d = (s > 0.0f) ? sqrtf(s) : 0.0f;
            wk[k] = fmaxf(1.0f - d * inv_sigma, 0.0f);
        }
    }
    float accf[Fd];
    #pragma unroll
    for (int f = 0; f < Fd; ++f) accf[f] = 0.0f;
    const float* wt = weight + (size_t)t * Fd * Cd * Kd;
    for (int c = 0; c < Cd; ++c) {
        float xv[Kd];
        #pragma unroll
        for (int k = 0; k < Kd; ++k) xv[k] = xsf[c][tid + k];
        const float* wp = wt + c * Kd;
        #pragma unroll
        for (int k = 0; k < Kd; ++k) {
            float v = xv[k] * wk[k];
            #pragma unroll
            for (int f = 0; f < Fd; ++f)
                accf[f] = fmaf(v, wp[(size_t)f * Cd * Kd + k], accf[f]);
        }
    }
    float* op = out + (size_t)(b * Td + t) * Fd * Nd + n0 + tid;
    #pragma unroll
    for (int f = 0; f < Fd; ++f) op[(size_t)f * Nd] = accf[f];
}

extern "C" void kernel_launch(void* const* d_in, const int* in_sizes, int n_in,
                              void* d_out, int out_size, void* d_ws, size_t ws_size,
                              hipStream_t stream) {
    const float* x      = (const float*)d_in[0];
    const float* coords = (const float*)d_in[1];
    const float* weight = (const float*)d_in[2];
    const void*  sigma  = d_in[3];
    float* out = (float*)d_out;

    if (ws_size >= A_WS_BYTES) {
        unsigned short* aw = (unsigned short*)d_ws;
        prep_weights<<<(Td * Kd * 4 * 64 * 8 + 255) / 256, 256, 0, stream>>>(weight, aw);
        dim3 grid(Nd / NT, Td, Bd);
        swconv_mfma<<<grid, dim3(256), 0, stream>>>(x, coords, aw, sigma, out);
    } else {
        dim3 grid(Nd / NT, Td, Bd);
        swconv_f32_kernel<<<grid, dim3(256), 0, stream>>>(x, coords, weight, sigma, out);
    }
}

// Round 3
// 132.534 us; speedup vs baseline: 5.2650x; 1.0612x over previous
//
#include <hip/hip_runtime.h>
#include <math.h>

#define Bd   4
#define Td   4
#define Cd   32
#define Nd   16384
#define Fd   64
#define Kd   9
#define PADd 4
#define NT   128
#define NROWS (NT + 2*PADd)   // 136 staged n-positions (with halo)
#define NCHUNK (NROWS/4)      // 34 float4 chunks per channel row
#define XPITCH 140            // ushorts per c-row; 8-c stride = 560 dw ≡ 16 banks -> 2-way (free)

typedef __attribute__((ext_vector_type(8))) short  short8;   // MFMA A/B frag (8 bf16)
typedef __attribute__((ext_vector_type(4))) float  float4v;  // MFMA acc frag

#define A_WS_BYTES ((size_t)Td * Kd * 4 * 64 * 8 * 2)  // 147456

__device__ __forceinline__ float sigma_as_float(const void* p) {
    int iv = *(const int*)p;
    if (iv > 0 && iv < 1000000) return (float)iv;
    return __int_as_float(iv);
}

__device__ __forceinline__ unsigned short f32_to_bf16_rne(float v) {
    unsigned int a = __float_as_uint(v);
    a += 0x7fffu + ((a >> 16) & 1u);
    return (unsigned short)(a >> 16);
}

// ---- prep: weight fp32 [T][F][C][K] -> bf16 A-fragments in ws ----
// idx = (((t*K + k)*4 + ft)*64 + lane)*8 + j ; val = W[t][ft*16+(lane&15)][(lane>>4)*8+j][k]
__global__ void prep_weights(const float* __restrict__ w, unsigned short* __restrict__ a) {
    int idx = blockIdx.x * 256 + threadIdx.x;
    if (idx >= Td * Kd * 4 * 64 * 8) return;
    int j    = idx & 7;
    int lane = (idx >> 3) & 63;
    int ft   = (idx >> 9) & 3;
    int k    = (idx >> 11) % Kd;
    int t    = idx / (Kd * 4 * 64 * 8);
    int m = lane & 15, q = lane >> 4;
    int f = ft * 16 + m;
    int c = q * 8 + j;
    float v = w[(((size_t)t * Fd + f) * Cd + c) * Kd + k];
    a[idx] = f32_to_bf16_rne(v);
}

// ---- main kernel: per-k MFMA (C=0) then fp32 scale-accumulate ----
__global__ __launch_bounds__(256, 4)
void swconv_mfma2(const float* __restrict__ x,
                  const float* __restrict__ coords,
                  const unsigned short* __restrict__ aw,
                  const void* __restrict__ sigma_p,
                  float* __restrict__ out)
{
    __shared__ __align__(8) unsigned short xsn[Cd][XPITCH]; // 8960 B, bf16 natural layout
    __shared__ float wl[Kd][NT];                            // 4608 B

    const int tid  = threadIdx.x;
    const int lane = tid & 63;
    const int wv   = tid >> 6;          // wave 0..3, owns n_local [32*wv, 32*wv+32)
    const int tile = blockIdx.x, t = blockIdx.y, b = blockIdx.z;
    const int n0   = tile * NT;
    const float inv_sigma = 1.0f / sigma_as_float(sigma_p);

    // ---- stage x -> bf16, natural layout, float4 global loads ----
    // chunks are either fully in-bounds or fully out (halo=4, NT multiple of 4)
    const float* xbt = x + (size_t)(b * Td + t) * Cd * Nd;
    #pragma unroll 2
    for (int i = tid; i < Cd * NCHUNK; i += 256) {
        int c  = i / NCHUNK;
        int rq = i - c * NCHUNK;
        int nf = n0 - PADd + rq * 4;
        float4 v = make_float4(0.f, 0.f, 0.f, 0.f);
        if (nf >= 0 && nf < Nd)
            v = *reinterpret_cast<const float4*>(xbt + (size_t)c * Nd + nf);
        ushort4 u;
        u.x = f32_to_bf16_rne(v.x);
        u.y = f32_to_bf16_rne(v.y);
        u.z = f32_to_bf16_rne(v.z);
        u.w = f32_to_bf16_rne(v.w);
        *reinterpret_cast<ushort4*>(&xsn[c][rq * 4]) = u;
    }

    // ---- distance weights wl[k][n_local]; 2 threads per n, k split 0..4 / 5..8 ----
    {
        const float* cbt = coords + (size_t)(b * Td + t) * 3 * Nd;
        int ln   = tid & (NT - 1);
        int half = tid >> 7;
        int n    = n0 + ln;
        float c0 = cbt[n], c1 = cbt[Nd + n], c2 = cbt[2 * Nd + n];
        int k0 = half ? 5 : 0, k1 = half ? Kd : 5;
        for (int k = k0; k < k1; ++k) {
            int nn = n + k - PADd;
            float d0, d1, d2;
            if (nn >= 0 && nn < Nd) {
                d0 = cbt[nn] - c0; d1 = cbt[Nd + nn] - c1; d2 = cbt[2 * Nd + nn] - c2;
            } else {
                d0 = -c0; d1 = -c1; d2 = -c2;
            }
            float s = d0 * d0 + d1 * d1 + d2 * d2;
            float d = (s > 0.0f) ? sqrtf(s) : 0.0f;
            wl[k][ln] = fmaxf(1.0f - d * inv_sigma, 0.0f);
        }
    }
    __syncthreads();

    const int m = lane & 15, q = lane >> 4;
    const unsigned short* Abase = aw + (size_t)t * Kd * 4 * 64 * 8 + (size_t)lane * 8;

    float4v acc[4][2];
    #pragma unroll
    for (int ft = 0; ft < 4; ++ft)
        #pragma unroll
        for (int nt = 0; nt < 2; ++nt)
            acc[ft][nt] = (float4v){0.f, 0.f, 0.f, 0.f};

    const float4v zero4 = {0.f, 0.f, 0.f, 0.f};

    // A-fragment double buffer (prefetch k+1 during k's MFMAs)
    short8 afr[2][4];
    #pragma unroll
    for (int ft = 0; ft < 4; ++ft)
        afr[0][ft] = *reinterpret_cast<const short8*>(Abase + (size_t)ft * 512);

    for (int k = 0; k < Kd; ++k) {
        const int cur = k & 1;
        if (k + 1 < Kd) {
            #pragma unroll
            for (int ft = 0; ft < 4; ++ft)
                afr[cur ^ 1][ft] = *reinterpret_cast<const short8*>(Abase + (size_t)((k + 1) * 4 + ft) * 512);
        }
        #pragma unroll
        for (int nt = 0; nt < 2; ++nt) {
            const int ncol = wv * 32 + nt * 16 + m;   // n_local of this lane's column
            const int r    = ncol + k;                // staged row = n_local + k  (tap nn = n + k - 4)
            const unsigned short* bp = &xsn[q * 8][r];
            // 8 ds_read_u16 at compile-time offsets, 2-way banks (free); pack to bf16x2
            unsigned int p0 = (unsigned int)bp[0]          | ((unsigned int)bp[XPITCH]     << 16);
            unsigned int p1 = (unsigned int)bp[2 * XPITCH] | ((unsigned int)bp[3 * XPITCH] << 16);
            unsigned int p2 = (unsigned int)bp[4 * XPITCH] | ((unsigned int)bp[5 * XPITCH] << 16);
            unsigned int p3 = (unsigned int)bp[6 * XPITCH] | ((unsigned int)bp[7 * XPITCH] << 16);
            uint4 pk = {p0, p1, p2, p3};
            short8 bfr = *reinterpret_cast<short8*>(&pk);
            const float wgt = wl[k][ncol];
            #pragma unroll
            for (int ft = 0; ft < 4; ++ft) {
                float4v d = __builtin_amdgcn_mfma_f32_16x16x32_bf16(afr[cur][ft], bfr, zero4, 0, 0, 0);
                acc[ft][nt][0] = fmaf(wgt, d[0], acc[ft][nt][0]);
                acc[ft][nt][1] = fmaf(wgt, d[1], acc[ft][nt][1]);
                acc[ft][nt][2] = fmaf(wgt, d[2], acc[ft][nt][2]);
                acc[ft][nt][3] = fmaf(wgt, d[3], acc[ft][nt][3]);
            }
        }
    }

    // ---- epilogue: C/D layout col=lane&15 (n), row=(lane>>4)*4+reg (f) ----
    float* ob = out + (size_t)(b * Td + t) * Fd * Nd + n0;
    #pragma unroll
    for (int ft = 0; ft < 4; ++ft) {
        #pragma unroll
        for (int nt = 0; nt < 2; ++nt) {
            const int ncol = wv * 32 + nt * 16 + m;
            #pragma unroll
            for (int rr = 0; rr < 4; ++rr) {
                int f = ft * 16 + q * 4 + rr;
                ob[(size_t)f * Nd + ncol] = acc[ft][nt][rr];
            }
        }
    }
}

// ---- fallback fp32 kernel (ws too small) ----
__global__ __launch_bounds__(256, 4)
void swconv_f32_kernel(const float* __restrict__ x,
                       const float* __restrict__ coords,
                       const float* __restrict__ weight,
                       const void*  __restrict__ sigma_p,
                       float* __restrict__ out)
{
    __shared__ float xsf[Cd][NROWS + 1];
    __shared__ float csf[3][NROWS + 1];
    const int tid = threadIdx.x;
    const int tile = blockIdx.x, t = blockIdx.y, b = blockIdx.z;
    const int n0 = tile * NT;
    const float inv_sigma = 1.0f / sigma_as_float(sigma_p);

    const float* xbt = x + (size_t)(b * Td + t) * Cd * Nd;
    for (int idx = tid; idx < Cd * NROWS; idx += 256) {
        int c = idx / NROWS, i = idx - c * NROWS, n = n0 - PADd + i;
        xsf[c][i] = (n >= 0 && n < Nd) ? xbt[(size_t)c * Nd + n] : 0.0f;
    }
    const float* cbt = coords + (size_t)(b * Td + t) * 3 * Nd;
    for (int idx = tid; idx < 3 * NROWS; idx += 256) {
        int c = idx / NROWS, i = idx - c * NROWS, n = n0 - PADd + i;
        csf[c][i] = (n >= 0 && n < Nd) ? cbt[(size_t)c * Nd + n] : 0.0f;
    }
    __syncthreads();
    if (tid >= NT) return;

    float wk[Kd];
    {
        const float c0 = csf[0][tid + PADd], c1 = csf[1][tid + PADd], c2 = csf[2][tid + PADd];
        #pragma unroll
        for (int k = 0; k < Kd; ++k) {
            float d0 = csf[0][tid + k] - c0, d1 = csf[1][tid + k] - c1, d2 = csf[2][tid + k] - c2;
            float s = d0 * d0 + d1 * d1 + d2 * d2;
            float d = (s > 0.0f) ? sqrtf(s) : 0.0f;
            wk[k] = fmaxf(1.0f - d * inv_sigma, 0.0f);
        }
    }
    float accf[Fd];
    #pragma unroll
    for (int f = 0; f < Fd; ++f) accf[f] = 0.0f;
    const float* wt = weight + (size_t)t * Fd * Cd * Kd;
    for (int c = 0; c < Cd; ++c) {
        float xv[Kd];
        #pragma unroll
        for (int k = 0; k < Kd; ++k) xv[k] = xsf[c][tid + k];
        const float* wp = wt + c * Kd;
        #pragma unroll
        for (int k = 0; k < Kd; ++k) {
            float v = xv[k] * wk[k];
            #pragma unroll
            for (int f = 0; f < Fd; ++f)
                accf[f] = fmaf(v, wp[(size_t)f * Cd * Kd + k], accf[f]);
        }
    }
    float* op = out + (size_t)(b * Td + t) * Fd * Nd + n0 + tid;
    #pragma unroll
    for (int f = 0; f < Fd; ++f) op[(size_t)f * Nd] = accf[f];
}

extern "C" void kernel_launch(void* const* d_in, const int* in_sizes, int n_in,
                              void* d_out, int out_size, void* d_ws, size_t ws_size,
                              hipStream_t stream) {
    const float* x      = (const float*)d_in[0];
    const float* coords = (const float*)d_in[1];
    const float* weight = (const float*)d_in[2];
    const void*  sigma  = d_in[3];
    float* out = (float*)d_out;

    if (ws_size >= A_WS_BYTES) {
        unsigned short* aw = (unsigned short*)d_ws;
        prep_weights<<<(Td * Kd * 4 * 64 * 8 + 255) / 256, 256, 0, stream>>>(weight, aw);
        dim3 grid(Nd / NT, Td, Bd);   // 128 x 4 x 4 = 2048 blocks
        swconv_mfma2<<<grid, dim3(256), 0, stream>>>(x, coords, aw, sigma, out);
    } else {
        dim3 grid(Nd / NT, Td, Bd);
        swconv_f32_kernel<<<grid, dim3(256), 0, stream>>>(x, coords, weight, sigma, out);
    }
}

// Round 4
// 129.959 us; speedup vs baseline: 5.3693x; 1.0198x over previous
//
#include <hip/hip_runtime.h>
#include <math.h>

#define Bd   4
#define Td   4
#define Cd   32
#define Nd   16384
#define Fd   64
#define Kd   9
#define PADd 4
#define NT   128
#define NROWS (NT + 2*PADd)   // 136
#define NCHUNK (NROWS/4)      // 34 float4 chunks per channel row
#define XPITCH 140            // ushorts per c-row
#define EPIT 36               // epilogue pitch (dwords): 32 + 4 pad

typedef __attribute__((ext_vector_type(8))) short  short8;
typedef __attribute__((ext_vector_type(4))) float  float4v;

#define A_WS_BYTES ((size_t)Td * Kd * 4 * 64 * 8 * 2)  // 147456

// LDS layout (bytes):
//   staging phase: xsn [0,8960) | wl [8960,13568) | cs [13568,15200)
//   epilogue:      epi [0,18432)  (per-wave 4608 B) -- reused after barrier
#define SM_XSN 0
#define SM_WL  8960
#define SM_CS  13568
#define SM_BYTES 18432

__device__ __forceinline__ float sigma_as_float(const void* p) {
    int iv = *(const int*)p;
    if (iv > 0 && iv < 1000000) return (float)iv;
    return __int_as_float(iv);
}

__device__ __forceinline__ unsigned short f32_to_bf16_rne(float v) {
    unsigned int a = __float_as_uint(v);
    a += 0x7fffu + ((a >> 16) & 1u);
    return (unsigned short)(a >> 16);
}

// ---- prep: weight fp32 [T][F][C][K] -> bf16 A-fragments in ws ----
__global__ void prep_weights(const float* __restrict__ w, unsigned short* __restrict__ a) {
    int idx = blockIdx.x * 256 + threadIdx.x;
    if (idx >= Td * Kd * 4 * 64 * 8) return;
    int j    = idx & 7;
    int lane = (idx >> 3) & 63;
    int ft   = (idx >> 9) & 3;
    int k    = (idx >> 11) % Kd;
    int t    = idx / (Kd * 4 * 64 * 8);
    int m = lane & 15, q = lane >> 4;
    int f = ft * 16 + m;
    int c = q * 8 + j;
    float v = w[(((size_t)t * Fd + f) * Cd + c) * Kd + k];
    a[idx] = f32_to_bf16_rne(v);
}

__global__ __launch_bounds__(256, 4)
void swconv_mfma3(const float* __restrict__ x,
                  const float* __restrict__ coords,
                  const unsigned short* __restrict__ aw,
                  const void* __restrict__ sigma_p,
                  float* __restrict__ out)
{
    __shared__ __align__(16) unsigned char smem[SM_BYTES];
    unsigned short (*xsn)[XPITCH] = (unsigned short (*)[XPITCH])(smem + SM_XSN);
    float (*wl)[NT]               = (float (*)[NT])(smem + SM_WL);
    float (*cs)[NROWS]            = (float (*)[NROWS])(smem + SM_CS);

    const int tid  = threadIdx.x;
    const int lane = tid & 63;
    const int wv   = tid >> 6;          // wave 0..3, owns n_local [32*wv, 32*wv+32)
    const int tile = blockIdx.x, t = blockIdx.y, b = blockIdx.z;
    const int n0   = tile * NT;
    const float inv_sigma = 1.0f / sigma_as_float(sigma_p);

    // ---- stage x -> bf16 natural layout (float4 loads, ushort4 LDS writes) ----
    const float* xbt = x + (size_t)(b * Td + t) * Cd * Nd;
    #pragma unroll 2
    for (int i = tid; i < Cd * NCHUNK; i += 256) {
        int c  = i / NCHUNK;
        int rq = i - c * NCHUNK;
        int nf = n0 - PADd + rq * 4;
        float4 v = make_float4(0.f, 0.f, 0.f, 0.f);
        if (nf >= 0 && nf < Nd)
            v = *reinterpret_cast<const float4*>(xbt + (size_t)c * Nd + nf);
        ushort4 u;
        u.x = f32_to_bf16_rne(v.x);
        u.y = f32_to_bf16_rne(v.y);
        u.z = f32_to_bf16_rne(v.z);
        u.w = f32_to_bf16_rne(v.w);
        *reinterpret_cast<ushort4*>(&xsn[c][rq * 4]) = u;
    }

    // ---- stage coords (coalesced) ----
    const float* cbt = coords + (size_t)(b * Td + t) * 3 * Nd;
    for (int i = tid; i < 3 * NROWS; i += 256) {
        int c = i / NROWS, r = i - c * NROWS;
        int n = n0 - PADd + r;
        cs[c][r] = (n >= 0 && n < Nd) ? cbt[(size_t)c * Nd + n] : 0.0f;
    }

    // ---- A-fragment prefetch for k=0 (L2-hot, independent of LDS) ----
    const int m = lane & 15, q = lane >> 4;
    const unsigned short* Abase = aw + (size_t)t * Kd * 4 * 64 * 8 + (size_t)lane * 8;
    short8 afr[2][4];
    #pragma unroll
    for (int ft = 0; ft < 4; ++ft)
        afr[0][ft] = *reinterpret_cast<const short8*>(Abase + (size_t)ft * 512);

    __syncthreads();

    // ---- distance weights: WAVE-PRIVATE (write & read same wave, no barrier) ----
    {
        int nl   = wv * 32 + (lane & 31);   // n_local in this wave's window
        int half = lane >> 5;               // k 0..4 / 5..8
        int il   = nl + PADd;               // center index in cs
        float c0 = cs[0][il], c1 = cs[1][il], c2 = cs[2][il];
        int k0 = half ? 5 : 0, k1 = half ? Kd : 5;
        #pragma unroll
        for (int k = k0; k < k1; ++k) {
            float d0 = cs[0][nl + k] - c0;
            float d1 = cs[1][nl + k] - c1;
            float d2 = cs[2][nl + k] - c2;
            float s = d0 * d0 + d1 * d1 + d2 * d2;
            float d = (s > 0.0f) ? sqrtf(s) : 0.0f;
            wl[k][nl] = fmaxf(1.0f - d * inv_sigma, 0.0f);
        }
    }

    float4v acc[4][2];
    #pragma unroll
    for (int ft = 0; ft < 4; ++ft)
        #pragma unroll
        for (int nt = 0; nt < 2; ++nt)
            acc[ft][nt] = (float4v){0.f, 0.f, 0.f, 0.f};
    const float4v zero4 = {0.f, 0.f, 0.f, 0.f};

    for (int k = 0; k < Kd; ++k) {
        const int cur = k & 1;
        if (k + 1 < Kd) {
            #pragma unroll
            for (int ft = 0; ft < 4; ++ft)
                afr[cur ^ 1][ft] = *reinterpret_cast<const short8*>(Abase + (size_t)((k + 1) * 4 + ft) * 512);
        }
        #pragma unroll
        for (int nt = 0; nt < 2; ++nt) {
            const int ncol = wv * 32 + nt * 16 + m;
            const int r    = ncol + k;
            const unsigned short* bp = &xsn[q * 8][r];
            unsigned int p0 = (unsigned int)bp[0]          | ((unsigned int)bp[XPITCH]     << 16);
            unsigned int p1 = (unsigned int)bp[2 * XPITCH] | ((unsigned int)bp[3 * XPITCH] << 16);
            unsigned int p2 = (unsigned int)bp[4 * XPITCH] | ((unsigned int)bp[5 * XPITCH] << 16);
            unsigned int p3 = (unsigned int)bp[6 * XPITCH] | ((unsigned int)bp[7 * XPITCH] << 16);
            uint4 pk = {p0, p1, p2, p3};
            short8 bfr = *reinterpret_cast<short8*>(&pk);
            const float wgt = wl[k][ncol];
            #pragma unroll
            for (int ft = 0; ft < 4; ++ft) {
                float4v d = __builtin_amdgcn_mfma_f32_16x16x32_bf16(afr[cur][ft], bfr, zero4, 0, 0, 0);
                acc[ft][nt][0] = fmaf(wgt, d[0], acc[ft][nt][0]);
                acc[ft][nt][1] = fmaf(wgt, d[1], acc[ft][nt][1]);
                acc[ft][nt][2] = fmaf(wgt, d[2], acc[ft][nt][2]);
                acc[ft][nt][3] = fmaf(wgt, d[3], acc[ft][nt][3]);
            }
        }
    }

    // ---- epilogue: LDS transpose -> full-line float4 stores ----
    __syncthreads();   // protect xsn/wl from epi overwrite while others compute
    float (*epi)[EPIT] = (float (*)[EPIT])(smem + (size_t)wv * 32 * EPIT * 4);  // per-wave [32][36]

    float* ob = out + (size_t)(b * Td + t) * Fd * Nd + n0 + wv * 32;
    #pragma unroll
    for (int fc = 0; fc < 2; ++fc) {          // f chunks [0,32) / [32,64)
        #pragma unroll
        for (int ft2 = 0; ft2 < 2; ++ft2) {
            const int ft = fc * 2 + ft2;
            #pragma unroll
            for (int nt = 0; nt < 2; ++nt) {
                const int np = nt * 16 + m;
                #pragma unroll
                for (int rr = 0; rr < 4; ++rr)
                    epi[ft2 * 16 + q * 4 + rr][np] = acc[ft][nt][rr];
            }
        }
        // wave-internal RAW on LDS: compiler inserts lgkmcnt wait
        #pragma unroll
        for (int inst = 0; inst < 4; ++inst) {
            const int fl = inst * 8 + (lane >> 3);
            const int np = (lane & 7) * 4;
            float4 v = *reinterpret_cast<const float4*>(&epi[fl][np]);
            *reinterpret_cast<float4*>(ob + (size_t)(fc * 32 + fl) * Nd + np) = v;
        }
    }
}

// ---- fallback fp32 kernel (ws too small) ----
__global__ __launch_bounds__(256, 4)
void swconv_f32_kernel(const float* __restrict__ x,
                       const float* __restrict__ coords,
                       const float* __restrict__ weight,
                       const void*  __restrict__ sigma_p,
                       float* __restrict__ out)
{
    __shared__ float xsf[Cd][NROWS + 1];
    __shared__ float csf[3][NROWS + 1];
    const int tid = threadIdx.x;
    const int tile = blockIdx.x, t = blockIdx.y, b = blockIdx.z;
    const int n0 = tile * NT;
    const float inv_sigma = 1.0f / sigma_as_float(sigma_p);

    const float* xbt = x + (size_t)(b * Td + t) * Cd * Nd;
    for (int idx = tid; idx < Cd * NROWS; idx += 256) {
        int c = idx / NROWS, i = idx - c * NROWS, n = n0 - PADd + i;
        xsf[c][i] = (n >= 0 && n < Nd) ? xbt[(size_t)c * Nd + n] : 0.0f;
    }
    const float* cbt = coords + (size_t)(b * Td + t) * 3 * Nd;
    for (int idx = tid; idx < 3 * NROWS; idx += 256) {
        int c = idx / NROWS, i = idx - c * NROWS, n = n0 - PADd + i;
        csf[c][i] = (n >= 0 && n < Nd) ? cbt[(size_t)c * Nd + n] : 0.0f;
    }
    __syncthreads();
    if (tid >= NT) return;

    float wk[Kd];
    {
        const float c0 = csf[0][tid + PADd], c1 = csf[1][tid + PADd], c2 = csf[2][tid + PADd];
        #pragma unroll
        for (int k = 0; k < Kd; ++k) {
            float d0 = csf[0][tid + k] - c0, d1 = csf[1][tid + k] - c1, d2 = csf[2][tid + k] - c2;
            float s = d0 * d0 + d1 * d1 + d2 * d2;
            float d = (s > 0.0f) ? sqrtf(s) : 0.0f;
            wk[k] = fmaxf(1.0f - d * inv_sigma, 0.0f);
        }
    }
    float accf[Fd];
    #pragma unroll
    for (int f = 0; f < Fd; ++f) accf[f] = 0.0f;
    const float* wt = weight + (size_t)t * Fd * Cd * Kd;
    for (int c = 0; c < Cd; ++c) {
        float xv[Kd];
        #pragma unroll
        for (int k = 0; k < Kd; ++k) xv[k] = xsf[c][tid + k];
        const float* wp = wt + c * Kd;
        #pragma unroll
        for (int k = 0; k < Kd; ++k) {
            float v = xv[k] * wk[k];
            #pragma unroll
            for (int f = 0; f < Fd; ++f)
                accf[f] = fmaf(v, wp[(size_t)f * Cd * Kd + k], accf[f]);
        }
    }
    float* op = out + (size_t)(b * Td + t) * Fd * Nd + n0 + tid;
    #pragma unroll
    for (int f = 0; f < Fd; ++f) op[(size_t)f * Nd] = accf[f];
}

extern "C" void kernel_launch(void* const* d_in, const int* in_sizes, int n_in,
                              void* d_out, int out_size, void* d_ws, size_t ws_size,
                              hipStream_t stream) {
    const float* x      = (const float*)d_in[0];
    const float* coords = (const float*)d_in[1];
    const float* weight = (const float*)d_in[2];
    const void*  sigma  = d_in[3];
    float* out = (float*)d_out;

    if (ws_size >= A_WS_BYTES) {
        unsigned short* aw = (unsigned short*)d_ws;
        prep_weights<<<(Td * Kd * 4 * 64 * 8 + 255) / 256, 256, 0, stream>>>(weight, aw);
        dim3 grid(Nd / NT, Td, Bd);   // 2048 blocks
        swconv_mfma3<<<grid, dim3(256), 0, stream>>>(x, coords, aw, sigma, out);
    } else {
        dim3 grid(Nd / NT, Td, Bd);
        swconv_f32_kernel<<<grid, dim3(256), 0, stream>>>(x, coords, weight, sigma, out);
    }
}

// Round 5
// 111.336 us; speedup vs baseline: 6.2675x; 1.1673x over previous
//
#include <hip/hip_runtime.h>
#include <math.h>

#define Bd   4
#define Td   4
#define Cd   32
#define Nd   16384
#define Fd   64
#define Kd   9
#define PADd 4
#define NT   128
#define NROWS (NT + 2*PADd)   // 136
#define NCHUNK (NROWS/4)      // 34 float4 chunks per channel row
#define XP    40              // ushorts per transposed row: 32 c + 8 pad; 80 B pitch (16B-aligned)
#define EPIT  36              // epilogue pitch (dwords)

typedef __attribute__((ext_vector_type(8))) _Float16 half8;   // MFMA A/B frag (4 VGPRs)
typedef __attribute__((ext_vector_type(4))) float    float4v; // MFMA acc frag

#define A_WS_BYTES ((size_t)Td * Kd * 4 * 64 * 8 * 2)  // 147456

// LDS layout (bytes):
//   staging: xt [0,10880) | wlp [10880,15488) | cs [15488,17120)
//   epilogue: epi [0,18432) per-wave 4608 B (reused after barrier)
#define SM_XT  0
#define SM_WL  10880
#define SM_CS  15488
#define SM_BYTES 18432

union FragU { uint4 u; half8 h; };

__device__ __forceinline__ float sigma_as_float(const void* p) {
    int iv = *(const int*)p;
    if (iv > 0 && iv < 1000000) return (float)iv;
    return __int_as_float(iv);
}

__device__ __forceinline__ unsigned short f32_to_f16_bits(float f) {
    _Float16 h = (_Float16)f;           // v_cvt_f16_f32, RNE
    return *reinterpret_cast<unsigned short*>(&h);
}

// ---- prep: weight fp32 [T][F][C][K] -> fp16 A-fragments in ws ----
// idx = (((t*K + k)*4 + ft)*64 + lane)*8 + j ; val = W[t][ft*16+(lane&15)][(lane>>4)*8+j][k]
__global__ void prep_weights(const float* __restrict__ w, unsigned short* __restrict__ a) {
    int idx = blockIdx.x * 256 + threadIdx.x;
    if (idx >= Td * Kd * 4 * 64 * 8) return;
    int j    = idx & 7;
    int lane = (idx >> 3) & 63;
    int ft   = (idx >> 9) & 3;
    int k    = (idx >> 11) % Kd;
    int t    = idx / (Kd * 4 * 64 * 8);
    int m = lane & 15, q = lane >> 4;
    int f = ft * 16 + m;
    int c = q * 8 + j;
    float v = w[(((size_t)t * Fd + f) * Cd + c) * Kd + k];
    a[idx] = f32_to_f16_bits(v);
}

__global__ __launch_bounds__(256, 4)
void swconv_mfma4(const float* __restrict__ x,
                  const float* __restrict__ coords,
                  const unsigned short* __restrict__ aw,
                  const void* __restrict__ sigma_p,
                  float* __restrict__ out)
{
    __shared__ __align__(16) unsigned char smem[SM_BYTES];
    unsigned short (*xt)[XP] = (unsigned short (*)[XP])(smem + SM_XT);   // [NROWS][XP] fp16, transposed
    unsigned int (*wlp)[NT]  = (unsigned int (*)[NT])(smem + SM_WL);    // packed (h,h) per (k, n_local)
    float (*cs)[NROWS]       = (float (*)[NROWS])(smem + SM_CS);

    const int tid  = threadIdx.x;
    const int lane = tid & 63;
    const int wv   = tid >> 6;          // wave 0..3, owns n_local [32*wv, 32*wv+32)
    const int tile = blockIdx.x, t = blockIdx.y, b = blockIdx.z;
    const int n0   = tile * NT;
    const float inv_sigma = 1.0f / sigma_as_float(sigma_p);

    // ---- stage x -> fp16 TRANSPOSED xt[r][c] (float4 global loads) ----
    const float* xbt = x + (size_t)(b * Td + t) * Cd * Nd;
    #pragma unroll 2
    for (int i = tid; i < Cd * NCHUNK; i += 256) {
        int c  = i / NCHUNK;
        int rq = i - c * NCHUNK;
        int nf = n0 - PADd + rq * 4;
        float4 v = make_float4(0.f, 0.f, 0.f, 0.f);
        if (nf >= 0 && nf < Nd)
            v = *reinterpret_cast<const float4*>(xbt + (size_t)c * Nd + nf);
        int r = rq * 4;
        xt[r + 0][c] = f32_to_f16_bits(v.x);
        xt[r + 1][c] = f32_to_f16_bits(v.y);
        xt[r + 2][c] = f32_to_f16_bits(v.z);
        xt[r + 3][c] = f32_to_f16_bits(v.w);
    }

    // ---- stage coords (coalesced) ----
    const float* cbt = coords + (size_t)(b * Td + t) * 3 * Nd;
    for (int i = tid; i < 3 * NROWS; i += 256) {
        int c = i / NROWS, r = i - c * NROWS;
        int n = n0 - PADd + r;
        cs[c][r] = (n >= 0 && n < Nd) ? cbt[(size_t)c * Nd + n] : 0.0f;
    }

    // ---- A-fragment prefetch k=0 (L2-hot, independent of LDS) ----
    const int m = lane & 15, q = lane >> 4;
    const unsigned short* Abase = aw + (size_t)t * Kd * 4 * 64 * 8 + (size_t)lane * 8;
    FragU afr[2][4];
    #pragma unroll
    for (int ft = 0; ft < 4; ++ft)
        afr[0][ft].u = *reinterpret_cast<const uint4*>(Abase + (size_t)ft * 512);

    __syncthreads();

    // ---- distance weights (wave-private: write & read by same wave) ----
    {
        int nl   = wv * 32 + (lane & 31);
        int half = lane >> 5;               // k 0..4 / 5..8
        int il   = nl + PADd;
        float c0 = cs[0][il], c1 = cs[1][il], c2 = cs[2][il];
        int k0 = half ? 5 : 0, k1 = half ? Kd : 5;
        #pragma unroll
        for (int k = k0; k < k1; ++k) {
            float d0 = cs[0][nl + k] - c0;
            float d1 = cs[1][nl + k] - c1;
            float d2 = cs[2][nl + k] - c2;
            float s = d0 * d0 + d1 * d1 + d2 * d2;
            float d = (s > 0.0f) ? sqrtf(s) : 0.0f;
            float w = fmaxf(1.0f - d * inv_sigma, 0.0f);
            wlp[k][nl] = (unsigned int)f32_to_f16_bits(w) * 0x00010001u;  // (h,h)
        }
    }

    float4v acc[4][2];
    #pragma unroll
    for (int ft = 0; ft < 4; ++ft)
        #pragma unroll
        for (int nt = 0; nt < 2; ++nt)
            acc[ft][nt] = (float4v){0.f, 0.f, 0.f, 0.f};

    for (int k = 0; k < Kd; ++k) {
        const int cur = k & 1;
        if (k + 1 < Kd) {
            #pragma unroll
            for (int ft = 0; ft < 4; ++ft)
                afr[cur ^ 1][ft].u = *reinterpret_cast<const uint4*>(Abase + (size_t)((k + 1) * 4 + ft) * 512);
        }
        #pragma unroll
        for (int nt = 0; nt < 2; ++nt) {
            const int ncol = wv * 32 + nt * 16 + m;   // n_local of this lane's column
            const int r    = ncol + k;                // xt row (tap nn = n + k - 4)
            FragU xv; xv.u = *reinterpret_cast<const uint4*>(&xt[r][q * 8]);  // 8 c's, one ds_read_b128
            unsigned int wp = wlp[k][ncol];
            FragU ww; ww.u = make_uint4(wp, wp, wp, wp);
            half8 bfr = xv.h * ww.h;                  // 4x v_pk_mul_f16
            #pragma unroll
            for (int ft = 0; ft < 4; ++ft)
                acc[ft][nt] = __builtin_amdgcn_mfma_f32_16x16x32_f16(afr[cur][ft].h, bfr, acc[ft][nt], 0, 0, 0);
        }
    }

    // ---- epilogue: LDS transpose -> full-line float4 stores ----
    __syncthreads();   // xt/wlp dead for everyone before epi overwrite
    float (*epi)[EPIT] = (float (*)[EPIT])(smem + (size_t)wv * 32 * EPIT * 4);  // per-wave [32][36]

    float* ob = out + (size_t)(b * Td + t) * Fd * Nd + n0 + wv * 32;
    #pragma unroll
    for (int fc = 0; fc < 2; ++fc) {          // f chunks [0,32) / [32,64)
        #pragma unroll
        for (int ft2 = 0; ft2 < 2; ++ft2) {
            const int ft = fc * 2 + ft2;
            #pragma unroll
            for (int nt = 0; nt < 2; ++nt) {
                const int np = nt * 16 + m;
                #pragma unroll
                for (int rr = 0; rr < 4; ++rr)
                    epi[ft2 * 16 + q * 4 + rr][np] = acc[ft][nt][rr];
            }
        }
        #pragma unroll
        for (int inst = 0; inst < 4; ++inst) {
            const int fl = inst * 8 + (lane >> 3);
            const int np = (lane & 7) * 4;
            float4 v = *reinterpret_cast<const float4*>(&epi[fl][np]);
            *reinterpret_cast<float4*>(ob + (size_t)(fc * 32 + fl) * Nd + np) = v;
        }
    }
}

// ---- fallback fp32 kernel (ws too small) ----
__global__ __launch_bounds__(256, 4)
void swconv_f32_kernel(const float* __restrict__ x,
                       const float* __restrict__ coords,
                       const float* __restrict__ weight,
                       const void*  __restrict__ sigma_p,
                       float* __restrict__ out)
{
    __shared__ float xsf[Cd][NROWS + 1];
    __shared__ float csf[3][NROWS + 1];
    const int tid = threadIdx.x;
    const int tile = blockIdx.x, t = blockIdx.y, b = blockIdx.z;
    const int n0 = tile * NT;
    const float inv_sigma = 1.0f / sigma_as_float(sigma_p);

    const float* xbt = x + (size_t)(b * Td + t) * Cd * Nd;
    for (int idx = tid; idx < Cd * NROWS; idx += 256) {
        int c = idx / NROWS, i = idx - c * NROWS, n = n0 - PADd + i;
        xsf[c][i] = (n >= 0 && n < Nd) ? xbt[(size_t)c * Nd + n] : 0.0f;
    }
    const float* cbt = coords + (size_t)(b * Td + t) * 3 * Nd;
    for (int idx = tid; idx < 3 * NROWS; idx += 256) {
        int c = idx / NROWS, i = idx - c * NROWS, n = n0 - PADd + i;
        csf[c][i] = (n >= 0 && n < Nd) ? cbt[(size_t)c * Nd + n] : 0.0f;
    }
    __syncthreads();
    if (tid >= NT) return;

    float wk[Kd];
    {
        const float c0 = csf[0][tid + PADd], c1 = csf[1][tid + PADd], c2 = csf[2][tid + PADd];
        #pragma unroll
        for (int k = 0; k < Kd; ++k) {
            float d0 = csf[0][tid + k] - c0, d1 = csf[1][tid + k] - c1, d2 = csf[2][tid + k] - c2;
            float s = d0 * d0 + d1 * d1 + d2 * d2;
            float d = (s > 0.0f) ? sqrtf(s) : 0.0f;
            wk[k] = fmaxf(1.0f - d * inv_sigma, 0.0f);
        }
    }
    float accf[Fd];
    #pragma unroll
    for (int f = 0; f < Fd; ++f) accf[f] = 0.0f;
    const float* wt = weight + (size_t)t * Fd * Cd * Kd;
    for (int c = 0; c < Cd; ++c) {
        float xv[Kd];
        #pragma unroll
        for (int k = 0; k < Kd; ++k) xv[k] = xsf[c][tid + k];
        const float* wp = wt + c * Kd;
        #pragma unroll
        for (int k = 0; k < Kd; ++k) {
            float v = xv[k] * wk[k];
            #pragma unroll
            for (int f = 0; f < Fd; ++f)
                accf[f] = fmaf(v, wp[(size_t)f * Cd * Kd + k], accf[f]);
        }
    }
    float* op = out + (size_t)(b * Td + t) * Fd * Nd + n0 + tid;
    #pragma unroll
    for (int f = 0; f < Fd; ++f) op[(size_t)f * Nd] = accf[f];
}

extern "C" void kernel_launch(void* const* d_in, const int* in_sizes, int n_in,
                              void* d_out, int out_size, void* d_ws, size_t ws_size,
                              hipStream_t stream) {
    const float* x      = (const float*)d_in[0];
    const float* coords = (const float*)d_in[1];
    const float* weight = (const float*)d_in[2];
    const void*  sigma  = d_in[3];
    float* out = (float*)d_out;

    if (ws_size >= A_WS_BYTES) {
        unsigned short* aw = (unsigned short*)d_ws;
        prep_weights<<<(Td * Kd * 4 * 64 * 8 + 255) / 256, 256, 0, stream>>>(weight, aw);
        dim3 grid(Nd / NT, Td, Bd);   // 2048 blocks
        swconv_mfma4<<<grid, dim3(256), 0, stream>>>(x, coords, aw, sigma, out);
    } else {
        dim3 grid(Nd / NT, Td, Bd);
        swconv_f32_kernel<<<grid, dim3(256), 0, stream>>>(x, coords, weight, sigma, out);
    }
}